// Round 7
// baseline (106.391 us; speedup 1.0000x reference)
//
#include <hip/hip_runtime.h>

// Problem constants (match reference): B=64, L=2048, H=256, K=32
#define LL 2048
#define BB 64
#define HH 256
#define KK 32

#define NB  2048   // 8 blocks/CU -> 32 waves/CU grid cap
#define WPB 4      // waves per block

typedef __attribute__((ext_vector_type(8))) short  short8;   // 8 bf16 (4 VGPRs)
typedef __attribute__((ext_vector_type(4))) float  f32x4;

__device__ __forceinline__ float softplus_f(float x) {
    return x > 20.f ? x : __logf(1.f + __expf(x));
}
// round-to-nearest-even fp32 -> bf16
__device__ __forceinline__ unsigned f2bf(float x) {
    unsigned u = __builtin_bit_cast(unsigned, x);
    return (u + 0x7FFFu + ((u >> 16) & 1u)) >> 16;
}
__device__ __forceinline__ short8 pack_bf16x8(float4 a, float4 b) {
    union { unsigned u[4]; short8 s; } r;
    r.u[0] = f2bf(a.x) | (f2bf(a.y) << 16);
    r.u[1] = f2bf(a.z) | (f2bf(a.w) << 16);
    r.u[2] = f2bf(b.x) | (f2bf(b.y) << 16);
    r.u[3] = f2bf(b.z) | (f2bf(b.w) << 16);
    return r.s;
}

// 8 flat rows per wave-tile. A-frag rows 0-7 = v (lanes m<8 compute),
// rows 8-15 = hidden (lanes m>=8, loads only). One C[16][32]:
// rows 0-7 v-dots (term2), rows 8-15 h-dots (term1). W^T B-fragments
// staged once to LDS (swizzled), read once per wave into 64 VGPRs.
__global__ __launch_bounds__(256) void nhll_main(
    const int*   __restrict__ events,   // [B, L]
    const int*   __restrict__ lens,     // [B]
    const float* __restrict__ ttime,    // [B]
    const float* __restrict__ hidden,   // [L, B, H]
    const float* __restrict__ cell,     // [L, B, H]
    const float* __restrict__ ctarg,    // [L, B, H]
    const float* __restrict__ outp,     // [L, B, H]
    const float* __restrict__ decay,    // [L, B, H]
    const float* __restrict__ simt,     // [L, B]
    const float* __restrict__ W,        // [H, K]
    const float* __restrict__ bias,     // [K]
    float*       __restrict__ partial)  // [NB]
{
    __shared__ __align__(16) char  WTs[KK * HH * 2];   // bf16 W^T fragments, 16 KB
    __shared__ int   pfx[BB + 1];
    __shared__ float coef_s[BB];
    __shared__ float wacc[WPB];

    const int tid  = threadIdx.x;
    const int lane = tid & 63;
    const int q    = tid >> 6;
    const int g    = lane >> 4;     // k-octet selector
    const int m    = lane & 15;     // A-row / C-col index

    // ---- one-time: stage W as bf16 fragments in LDS (swizzled) ----
    {
        const float* wrow = &W[tid * KK];        // h-row tid
#pragma unroll
        for (int k = 0; k < KK; ++k) {
            const int byte = (k * 512 + tid * 2) ^ ((k & 7) << 4);
            *(unsigned short*)(WTs + byte) = (unsigned short)f2bf(wrow[k]);
        }
    }
    if (tid < BB) {                 // wave 0: scan lens -> prefix sums
        const int ln = lens[tid];
        coef_s[tid] = ttime[tid] / (float)ln;
        int s = ln;
#pragma unroll
        for (int mm = 1; mm < 64; mm <<= 1) {
            const int t = __shfl_up(s, mm, 64);
            if (lane >= mm) s += t;
        }
        pfx[tid + 1] = s;
        if (tid == 0) pfx[0] = 0;
    }
    __syncthreads();

    // ---- per-wave: W^T B-fragments LDS -> 64 VGPRs ----
    short8 w0f[8], w1f[8];
#pragma unroll
    for (int c = 0; c < 8; ++c) {
        w0f[c] = *(const short8*)(WTs + ((m * 512 + 64 * c + 16 * g) ^ ((m & 7) << 4)));
        w1f[c] = *(const short8*)(WTs + (((16 + m) * 512 + 64 * c + 16 * g) ^ (((16 + m) & 7) << 4)));
    }
    const float b_lo = bias[m];
    const float b_hi = bias[16 + m];

    const int T      = pfx[BB];
    const int ntiles = (T + 7) >> 3;
    float acc = 0.f;

    for (int tile = blockIdx.x * WPB + q; tile < ntiles; tile += NB * WPB) {
        // lane handles flat row i = tile*8 + (m&7); lanes m and m+8 share a row
        int i = tile * 8 + (m & 7);
        const int valid = (i < T) ? 1 : 0;
        if (!valid) i = T - 1;                    // clamp; masked below
        int lo = 0, hi = BB;
#pragma unroll
        for (int s = 0; s < 6; ++s) {
            const int mid = (lo + hi) >> 1;
            if (pfx[mid] <= i) lo = mid; else hi = mid;
        }
        const int   b    = lo;
        const int   l    = i - pfx[b];
        const int   r    = l * BB + b;
        const float coef = valid ? coef_s[b] : 0.f;
        const int   e    = events[b * LL + l + 1];   // l+1 <= 2046: in-bounds
        const int   base = r * HH + 8 * g;

        short8 af[8];
        if (m < 8) {
            // v-rows: load cell/ctarg/outp/decay, compute o*tanh(c_sim)
            const float st = simt[r];
            const float* pc = cell  + base;
            const float* pt = ctarg + base;
            const float* po = outp  + base;
            const float* pd = decay + base;
#pragma unroll
            for (int c = 0; c < 8; ++c) {
                const float4 c0 = *(const float4*)(pc + 32 * c);
                const float4 c1 = *(const float4*)(pc + 32 * c + 4);
                const float4 t0 = *(const float4*)(pt + 32 * c);
                const float4 t1 = *(const float4*)(pt + 32 * c + 4);
                const float4 o0 = *(const float4*)(po + 32 * c);
                const float4 o1 = *(const float4*)(po + 32 * c + 4);
                const float4 d0 = *(const float4*)(pd + 32 * c);
                const float4 d1 = *(const float4*)(pd + 32 * c + 4);
                float4 v0, v1;
                float cs, e2;
                cs = t0.x + (c0.x - t0.x) * __expf(-d0.x * st); e2 = __expf(2.f * cs); v0.x = o0.x * ((e2 - 1.f) / (e2 + 1.f));
                cs = t0.y + (c0.y - t0.y) * __expf(-d0.y * st); e2 = __expf(2.f * cs); v0.y = o0.y * ((e2 - 1.f) / (e2 + 1.f));
                cs = t0.z + (c0.z - t0.z) * __expf(-d0.z * st); e2 = __expf(2.f * cs); v0.z = o0.z * ((e2 - 1.f) / (e2 + 1.f));
                cs = t0.w + (c0.w - t0.w) * __expf(-d0.w * st); e2 = __expf(2.f * cs); v0.w = o0.w * ((e2 - 1.f) / (e2 + 1.f));
                cs = t1.x + (c1.x - t1.x) * __expf(-d1.x * st); e2 = __expf(2.f * cs); v1.x = o1.x * ((e2 - 1.f) / (e2 + 1.f));
                cs = t1.y + (c1.y - t1.y) * __expf(-d1.y * st); e2 = __expf(2.f * cs); v1.y = o1.y * ((e2 - 1.f) / (e2 + 1.f));
                cs = t1.z + (c1.z - t1.z) * __expf(-d1.z * st); e2 = __expf(2.f * cs); v1.z = o1.z * ((e2 - 1.f) / (e2 + 1.f));
                cs = t1.w + (c1.w - t1.w) * __expf(-d1.w * st); e2 = __expf(2.f * cs); v1.w = o1.w * ((e2 - 1.f) / (e2 + 1.f));
                af[c] = pack_bf16x8(v0, v1);
            }
        } else {
            // hidden rows: loads only
            const float* ph = hidden + base;
#pragma unroll
            for (int c = 0; c < 8; ++c) {
                const float4 h0 = *(const float4*)(ph + 32 * c);
                const float4 h1 = *(const float4*)(ph + 32 * c + 4);
                af[c] = pack_bf16x8(h0, h1);
            }
        }

        f32x4 C0 = {0.f,0.f,0.f,0.f}, C1 = {0.f,0.f,0.f,0.f};
#pragma unroll
        for (int c = 0; c < 8; ++c) {
            C0 = __builtin_amdgcn_mfma_f32_16x16x32_bf16(af[c], w0f[c], C0, 0, 0, 0);
            C1 = __builtin_amdgcn_mfma_f32_16x16x32_bf16(af[c], w1f[c], C1, 0, 0, 0);
        }

        // ---- term 2: C rows 0-7 (g<2), row = 4g+reg, col = m ----
        float sp[4];
#pragma unroll
        for (int reg = 0; reg < 4; ++reg)
            sp[reg] = softplus_f(C0[reg] + b_lo) + softplus_f(C1[reg] + b_hi);
#pragma unroll
        for (int mk = 1; mk <= 8; mk <<= 1) {
#pragma unroll
            for (int reg = 0; reg < 4; ++reg) sp[reg] += __shfl_xor(sp[reg], mk, 64);
        }
        float t2 = 0.f;
#pragma unroll
        for (int reg = 0; reg < 4; ++reg) {
            const float cf = __shfl(coef, 4 * g + reg, 64);  // coef of flat row 4g+reg
            t2 += cf * sp[reg];
        }
        if (m == 0 && g < 2) acc += t2;

        // ---- term 1: C rows 8-15 (g=2,3) gathered at column e ----
        float kv = 0.f, kb = 0.f;
#pragma unroll
        for (int rr = 0; rr < 8; ++rr) {
            const int   er   = __shfl(e, rr, 64);            // e of flat row rr
            const float cand = (er < 16) ? C0[rr & 3] : C1[rr & 3];
            const float val  = __shfl(cand, 32 + ((rr >> 2) << 4) + (er & 15), 64);
            const float bsel = (er < 16) ? b_lo : b_hi;
            const float be   = __shfl(bsel, er & 15, 64);
            if (lane == rr) { kv = val; kb = be; }
        }
        if (lane < 8 && valid)
            acc -= __logf(softplus_f(kv + kb));
    }

    // wave reduce + block reduce
#pragma unroll
    for (int mk = 1; mk < 64; mk <<= 1) acc += __shfl_xor(acc, mk, 64);
    if (lane == 0) wacc[q] = acc;
    __syncthreads();
    if (tid == 0) partial[blockIdx.x] = wacc[0] + wacc[1] + wacc[2] + wacc[3];
}

// Output: single float32 scalar.
__global__ __launch_bounds__(256) void nhll_finalize(
    const float* __restrict__ partial, float* __restrict__ out)
{
    __shared__ float red[4];
    float s = 0.f;
    for (int i = threadIdx.x; i < NB; i += 256) s += partial[i];
    for (int mk = 1; mk < 64; mk <<= 1) s += __shfl_xor(s, mk, 64);
    if ((threadIdx.x & 63) == 0) red[threadIdx.x >> 6] = s;
    __syncthreads();
    if (threadIdx.x == 0)
        out[0] = red[0] + red[1] + red[2] + red[3];
}

extern "C" void kernel_launch(void* const* d_in, const int* in_sizes, int n_in,
                              void* d_out, int out_size, void* d_ws, size_t ws_size,
                              hipStream_t stream) {
    const int*   events = (const int*)  d_in[0];   // event_seqs  [B,L] int32
    const int*   lens   = (const int*)  d_in[1];   // seqs_length [B]   int32
    const float* ttime  = (const float*)d_in[2];   // total_time  [B]
    const float* hidden = (const float*)d_in[3];   // [L,B,H]
    const float* cell   = (const float*)d_in[4];   // [L,B,H]
    const float* ctarg  = (const float*)d_in[5];   // [L,B,H]
    const float* outp   = (const float*)d_in[6];   // [L,B,H]
    const float* decay  = (const float*)d_in[7];   // [L,B,H]
    const float* simt   = (const float*)d_in[8];   // [L,B]
    const float* W      = (const float*)d_in[9];   // [H,K]
    const float* bias   = (const float*)d_in[10];  // [K]

    float* part = (float*)d_ws;                    // NB floats (8 KB)
    float* out  = (float*)d_out;

    nhll_main<<<NB, 256, 0, stream>>>(events, lens, ttime, hidden, cell, ctarg,
                                      outp, decay, simt, W, bias, part);
    nhll_finalize<<<1, 256, 0, stream>>>(part, out);
}